// Round 8
// baseline (692.948 us; speedup 1.0000x reference)
//
#include <hip/hip_runtime.h>
#include <hip/hip_bf16.h>

// B=500000, NGI=13, NLOC=10
// diagRAR[b] = (1/dt)*sum_g dw[b,g]*(n[g,:].R)^2
//            + k[b]  *sum_g dw[b,g]*((nx[b,0,g,:].R)^2 + (nx[b,1,g,:].R)^2)
// rr1[b] = r1_1[b] - diagRAR[b]*e_i[b]
//
// Round-8: unit-stride vmem. Round-7 (~155us est) loaded 5 float4/thread at
// 80 B lane stride -> ~5x line-request rate at TA/L1 (bytes fine, requests
// not). Now the 39-b tile (2535 float4 = 40.5 KB) is staged to LDS with
// perfectly-coalesced stride-1 float4 loads (64 lanes x 16 B = 1024 B/instr),
// then per-group dots read from LDS (80 B stride ds_read_b128, ~4-way bank
// conflict = 1.58x on a non-critical path, m136).

#define NGI 13
#define NLOC 10
#define GRP_PER_B 13                  // 5-float4 groups per b
#define NX4_PER_B 65                  // float4s per b
#define TILE_B 39                     // b's per block
#define NX4_TILE (TILE_B * NX4_PER_B) // 2535 float4 = 40560 B
#define LOAD_T (TILE_B * GRP_PER_B)   // 507 dot threads
#define BLOCK 512
#define STAGE_ITERS 5                 // ceil(2535/512)

__global__ __launch_bounds__(BLOCK) void diag_rar_fused(
    const float* __restrict__ e_i,
    const float* __restrict__ r1_1,
    const float* __restrict__ k,
    const float* __restrict__ dt,
    const float* __restrict__ n,
    const float* __restrict__ nx,
    const float* __restrict__ detwei,
    const float* __restrict__ R,
    float* __restrict__ out_diag,
    float* __restrict__ out_rr1,
    int B)
{
    __shared__ float4 nx4s[NX4_TILE];        // 40560 B staged nx tile
    __shared__ float sq[TILE_B][2 * NGI];    // dot^2 per (local b, row)
    __shared__ float dwl[LOAD_T];            // detwei tile (39*13)

    const int t = threadIdx.x;
    const long tile_b0 = (long)blockIdx.x * TILE_B;
    const long nx4_base = tile_b0 * NX4_PER_B;
    const long nx4_total = (long)B * NX4_PER_B;
    const float4* __restrict__ src = reinterpret_cast<const float4*>(nx);

    // Stage nx tile: stride-1 across the block, fully coalesced.
#pragma unroll
    for (int i = 0; i < STAGE_ITERS; ++i) {
        const int idx = t + i * BLOCK;
        if (idx < NX4_TILE) {
            const long gidx = nx4_base + idx;
            if (gidx < nx4_total) nx4s[idx] = src[gidx];
        }
    }
    // Stage detwei tile: 507 threads == 39 b * 13 g, coalesced.
    if (t < LOAD_T) {
        const long dwi = tile_b0 * NGI + t;
        if (dwi < (long)B * NGI) dwl[t] = detwei[dwi];
    }

    __syncthreads();

    // R is uniform-address -> broadcast (L1-cached).
    const float R0 = R[0], R1 = R[1], R2 = R[2], R3 = R[3], R4 = R[4];
    const float R5 = R[5], R6 = R[6], R7 = R[7], R8 = R[8], R9 = R[9];

    if (t < LOAD_T) {
        const int lb = t / GRP_PER_B;       // local b: 0..38
        const int u  = t % GRP_PER_B;       // group within b: 0..12
        if (tile_b0 + lb < B) {
            const float4* p = &nx4s[lb * NX4_PER_B + u * 5];
            const float4 v0 = p[0], v1 = p[1], v2 = p[2], v3 = p[3], v4 = p[4];
            // rows 2u (A) and 2u+1 (B): A = v0 v1 v2.xy ; B = v2.zw v3 v4
            const float dA = v0.x * R0 + v0.y * R1 + v0.z * R2 + v0.w * R3
                           + v1.x * R4 + v1.y * R5 + v1.z * R6 + v1.w * R7
                           + v2.x * R8 + v2.y * R9;
            const float dB = v2.z * R0 + v2.w * R1
                           + v3.x * R2 + v3.y * R3 + v3.z * R4 + v3.w * R5
                           + v4.x * R6 + v4.y * R7 + v4.z * R8 + v4.w * R9;
            *reinterpret_cast<float2*>(&sq[lb][2 * u]) =
                make_float2(dA * dA, dB * dB);
        }
    }

    __syncthreads();

    if (t < TILE_B) {
        const long b = tile_b0 + t;
        if (b < B) {
            float nR2[NGI];
#pragma unroll
            for (int g = 0; g < NGI; ++g) {
                float s = 0.f;
#pragma unroll
                for (int i = 0; i < NLOC; ++i) s += n[g * NLOC + i] * R[i];
                nR2[g] = s * s;
            }
            float acc_k = 0.f, acc_n = 0.f;
#pragma unroll
            for (int g = 0; g < NGI; ++g) {
                const float dw = dwl[t * NGI + g];
                acc_k += dw * (sq[t][g] + sq[t][NGI + g]);
                acc_n += dw * nR2[g];
            }
            const float diag = acc_n * (1.0f / dt[0]) + k[b] * acc_k;
            out_diag[b] = diag;
            out_rr1[b] = r1_1[b] - diag * e_i[b];
        }
    }
}

extern "C" void kernel_launch(void* const* d_in, const int* in_sizes, int n_in,
                              void* d_out, int out_size, void* d_ws, size_t ws_size,
                              hipStream_t stream) {
    const float* e_i    = (const float*)d_in[0];
    const float* r1_1   = (const float*)d_in[1];
    const float* k      = (const float*)d_in[2];
    const float* dt     = (const float*)d_in[3];
    const float* n      = (const float*)d_in[4];
    const float* nx     = (const float*)d_in[5];
    const float* detwei = (const float*)d_in[6];
    const float* R      = (const float*)d_in[7];

    const int B = in_sizes[0]; // e_i is (B,1)
    float* out_diag = (float*)d_out;
    float* out_rr1  = (float*)d_out + B;

    const int grid = (B + TILE_B - 1) / TILE_B; // one 39-b tile per block
    diag_rar_fused<<<grid, BLOCK, 0, stream>>>(
        e_i, r1_1, k, dt, n, nx, detwei, R, out_diag, out_rr1, B);
}